// Round 12
// baseline (89.676 us; speedup 1.0000x reference)
//
#include <hip/hip_runtime.h>
#include <hip/hip_fp16.h>
#include <hip/hip_cooperative_groups.h>

// out[t,f,d] = sum_{c=0..9} table[x[t,f,c], d] * w[c],  w[c] = (10-c)/55
// x: (1024,64,10) int32; table: (8000,256) f32; out: (1024,64,256) f32
//
// R12: R10's validated structure (13 VMEM instrs / 2 row-equiv, permuted
// fp16 2-slice table, regular contiguous stores, slice<->XCD-parity
// affinity) fused into one cooperative kernel -- but ROBUSTLY this time:
//  - __launch_bounds__(256,2): VGPR <= 128 -> >=4 blocks/CU co-resident
//  - grid size from hipOccupancyMaxActiveBlocksPerMultiprocessor (<=1024,
//    multiple of 8), not assumed
//  - hipLaunchCooperativeKernel return code CHECKED; on any failure fall
//    back (same call) to the proven R10 two-dispatch path (29.6 us)
// R11's failure was an unchecked launch error -> all-zero output.
// Cost model (fits R2/R9/R10): TA line-touch ~4 cyc/128-B line/CU; per-CU
// ~12.4K lines -> main ~24-25 us; fusion recovers the ~3-4 us cvt+gap.

#define ROWS_TOTAL (1024 * 64)
#define TROWS 8000
#define TD 256
#define VBLKS 8192            // virtual blocks: (65536/16) * 2 slices

typedef float v4f __attribute__((ext_vector_type(4)));
typedef _Float16 h8 __attribute__((ext_vector_type(8)));

namespace cg = cooperative_groups;

__device__ __forceinline__ void cvt_chunk(const float* __restrict__ table,
                                          _Float16* __restrict__ tb,
                                          int c, int p) {
    // chunk c (16 B = 8 halfs) of (row, slice p) = dims [128p+4i,+4) U
    // [128p+64+4i,+4), row = c>>4, i = c&15.
    const int row = c >> 4;
    const int i   = c & 15;
    const float* src = table + (size_t)row * TD + p * 128 + 4 * i;
    v4f a = *reinterpret_cast<const v4f*>(src);
    v4f b = *reinterpret_cast<const v4f*>(src + 64);
    h8 r;
    r[0] = (_Float16)a.x; r[1] = (_Float16)a.y;
    r[2] = (_Float16)a.z; r[3] = (_Float16)a.w;
    r[4] = (_Float16)b.x; r[5] = (_Float16)b.y;
    r[6] = (_Float16)b.z; r[7] = (_Float16)b.w;
    __builtin_nontemporal_store(
        r, reinterpret_cast<h8*>(tb + ((size_t)row * 32 + p * 16 + i) * 8));
}

__device__ __forceinline__ void main_body(const int* __restrict__ x,
                                          const _Float16* __restrict__ tb,
                                          float* __restrict__ out,
                                          int vb, int l, int wv) {
    const int q = l >> 4;                  // quarter-wave -> row offset
    const int i = l & 15;                  // 16-B chunk within half-slice
    const int s       = vb & 1;            // d-half (== block parity)
    const int rowbase = (vb >> 1) * 16 + wv * 4;
    const int row     = rowbase + q;

    // 40 indices for the 4-row group in lanes 0..39 (one dword instr).
    const int t = x[rowbase * 10 + (l < 40 ? l : 39)];

    int idx[10];
#pragma unroll
    for (int c = 0; c < 10; ++c) idx[c] = __shfl(t, q * 10 + c);

    // 10 independent gathers; quarter-wave reads a 256-B permuted slice.
    h8 v[10];
#pragma unroll
    for (int c = 0; c < 10; ++c)
        v[c] = *reinterpret_cast<const h8*>(
            tb + (size_t)idx[c] * TD + s * 128 + i * 8);

    const float w[10] = {10.f / 55.f, 9.f / 55.f, 8.f / 55.f, 7.f / 55.f,
                         6.f / 55.f,  5.f / 55.f, 4.f / 55.f, 3.f / 55.f,
                         2.f / 55.f,  1.f / 55.f};

    float acc[8] = {0, 0, 0, 0, 0, 0, 0, 0};
#pragma unroll
    for (int c = 0; c < 10; ++c) {
#pragma unroll
        for (int e = 0; e < 8; ++e)
            acc[e] = fmaf((float)v[c][e], w[c], acc[e]);
    }

    // Regular stores; each instr writes 4 contiguous 256-B runs.
    v4f lo = {acc[0], acc[1], acc[2], acc[3]};
    v4f hi = {acc[4], acc[5], acc[6], acc[7]};
    float* orow = out + (size_t)row * TD + s * 128;
    *reinterpret_cast<v4f*>(orow + 4 * i)      = lo;
    *reinterpret_cast<v4f*>(orow + 64 + 4 * i) = hi;
}

// ---- fused cooperative kernel ----
__global__ __launch_bounds__(256, 2)
void char2vec_coop(const int* __restrict__ x,
                   const float* __restrict__ table,
                   _Float16* __restrict__ tb,
                   float* __restrict__ out) {
    const int p      = blockIdx.x & 1;     // parity -> slice (XCD affinity)
    const int halfId = blockIdx.x >> 1;
    const int nhalf  = gridDim.x >> 1;     // blocks per parity

    // phase 1: convert this parity's slice (grid-stride over 128000 chunks)
    for (int c = halfId * 256 + (int)threadIdx.x; c < TROWS * 16;
         c += nhalf * 256)
        cvt_chunk(table, tb, c, p);

    cg::this_grid().sync();

    // phase 2: R10 main body over virtual blocks (parity preserved:
    // gridDim.x is even, so vb & 1 == blockIdx.x & 1 == p).
    const int l  = threadIdx.x & 63;
    const int wv = threadIdx.x >> 6;
#pragma unroll 1
    for (int vb = blockIdx.x; vb < VBLKS; vb += gridDim.x)
        main_body(x, tb, out, vb, l, wv);
}

// ---- R10 two-dispatch fallback kernels (proven: 29.6 us) ----
__global__ __launch_bounds__(256)
void cvt_perm2(const float* __restrict__ t, _Float16* __restrict__ o) {
    const int tid = blockIdx.x * 256 + threadIdx.x;   // 0 .. 256000
    const int row = tid >> 5;
    const int s   = (tid >> 4) & 1;
    const int i   = tid & 15;
    if (row >= TROWS) return;
    const float* src = t + (size_t)row * TD + s * 128 + 4 * i;
    v4f a = *reinterpret_cast<const v4f*>(src);
    v4f b = *reinterpret_cast<const v4f*>(src + 64);
    h8 r;
    r[0] = (_Float16)a.x; r[1] = (_Float16)a.y;
    r[2] = (_Float16)a.z; r[3] = (_Float16)a.w;
    r[4] = (_Float16)b.x; r[5] = (_Float16)b.y;
    r[6] = (_Float16)b.z; r[7] = (_Float16)b.w;
    __builtin_nontemporal_store(r, reinterpret_cast<h8*>(o + (size_t)tid * 8));
}

__global__ __launch_bounds__(256)
void char2vec_w2(const int* __restrict__ x,
                 const _Float16* __restrict__ tb,
                 float* __restrict__ out) {
    const int l  = threadIdx.x & 63;
    const int wv = threadIdx.x >> 6;
    main_body(x, tb, out, blockIdx.x, l, wv);
}

// ---- fp32 single-dispatch fallback if ws too small ----
__global__ __launch_bounds__(256)
void char2vec_sliced2(const int* __restrict__ x,
                      const float* __restrict__ table,
                      float* __restrict__ out) {
    const int slice = blockIdx.x & 7;
    const int rgrp  = blockIdx.x >> 3;
    const int wave  = threadIdx.x >> 6;
    const int lane  = threadIdx.x & 63;

    const int row0 = rgrp * 64 + wave * 16 + (lane >> 3) * 2;
    const int row1 = row0 + 1;
    const int d    = slice * 32 + (lane & 7) * 4;

    const int2* __restrict__ xa = reinterpret_cast<const int2*>(x + row0 * 10);
    const int2* __restrict__ xb = reinterpret_cast<const int2*>(x + row1 * 10);
    int2 pa[5], pb[5];
#pragma unroll
    for (int i = 0; i < 5; ++i) pa[i] = xa[i];
#pragma unroll
    for (int i = 0; i < 5; ++i) pb[i] = xb[i];

    int ia[10], ib[10];
#pragma unroll
    for (int i = 0; i < 5; ++i) {
        ia[2 * i] = pa[i].x; ia[2 * i + 1] = pa[i].y;
        ib[2 * i] = pb[i].x; ib[2 * i + 1] = pb[i].y;
    }

    v4f va[10], vb[10];
#pragma unroll
    for (int c = 0; c < 10; ++c)
        va[c] = *reinterpret_cast<const v4f*>(table + (size_t)ia[c] * TD + d);
#pragma unroll
    for (int c = 0; c < 10; ++c)
        vb[c] = *reinterpret_cast<const v4f*>(table + (size_t)ib[c] * TD + d);

    const float w[10] = {10.f / 55.f, 9.f / 55.f, 8.f / 55.f, 7.f / 55.f,
                         6.f / 55.f,  5.f / 55.f, 4.f / 55.f, 3.f / 55.f,
                         2.f / 55.f,  1.f / 55.f};

    v4f acc0 = (v4f)0.0f, acc1 = (v4f)0.0f;
#pragma unroll
    for (int c = 0; c < 10; ++c) {
        acc0 += va[c] * w[c];
        acc1 += vb[c] * w[c];
    }

    *reinterpret_cast<v4f*>(out + (size_t)row0 * TD + d) = acc0;
    *reinterpret_cast<v4f*>(out + (size_t)row1 * TD + d) = acc1;
}

extern "C" void kernel_launch(void* const* d_in, const int* in_sizes, int n_in,
                              void* d_out, int out_size, void* d_ws, size_t ws_size,
                              hipStream_t stream) {
    const int*   x     = (const int*)d_in[0];
    const float* table = (const float*)d_in[1];
    float*       out   = (float*)d_out;

    const size_t f16_bytes = (size_t)TROWS * TD * sizeof(_Float16);

    if (ws_size >= f16_bytes) {
        _Float16* tb = (_Float16*)d_ws;

        // Derive a co-residency-safe grid for the cooperative launch.
        int occ = 0;
        hipError_t qerr = hipOccupancyMaxActiveBlocksPerMultiprocessor(
            &occ, char2vec_coop, 256, 0);
        int nblk = 0;
        if (qerr == hipSuccess && occ > 0) {
            long long cand = (long long)occ * 256;   // 256 CUs on MI355X
            if (cand > 1024) cand = 1024;
            nblk = (int)(cand & ~7LL);               // multiple of 8 (XCD/parity)
        }

        bool done = false;
        if (nblk >= 16) {
            void* args[4] = {(void*)&x, (void*)&table, (void*)&tb, (void*)&out};
            hipError_t e = hipLaunchCooperativeKernel(
                (const void*)char2vec_coop, dim3(nblk), dim3(256), args, 0,
                stream);
            if (e == hipSuccess) {
                done = true;
            } else {
                (void)hipGetLastError();   // clear sticky error, fall back
            }
        }

        if (!done) {
            // Proven R10 path.
            cvt_perm2<<<(TROWS * 32 + 255) / 256, 256, 0, stream>>>(table, tb);
            char2vec_w2<<<VBLKS, 256, 0, stream>>>(x, tb, out);
        }
    } else {
        const int blocks = (ROWS_TOTAL / 64) * 8;   // 8192
        char2vec_sliced2<<<blocks, 256, 0, stream>>>(x, table, out);
    }
}

// Round 13
// 29.599 us; speedup vs baseline: 3.0297x; 3.0297x over previous
//
#include <hip/hip_runtime.h>
#include <hip/hip_fp16.h>

// out[t,f,d] = sum_{c=0..9} table[x[t,f,c], d] * w[c],  w[c] = (10-c)/55
// x: (1024,64,10) int32; table: (8000,256) f32; out: (1024,64,256) f32
//
// R13 = exact revert to R10 (best validated: 29.6 us). R11/R12 proved the
// cooperative-fusion direction is net-negative (coop kernel 95 us: 1024
// co-resident blocks halve TLP on a latency-bound gather chain; the ~4 us
// of dispatch overhead is not worth it). Final structure:
//  - permuted fp16 table in d_ws, 2 d-slices; per-XCD slice 2 MB (L2-
//    resident with 2 MB write headroom); slice = blockIdx&1 -> XCD parity
//  - 13 VMEM instrs / 2 row-equivalents: 1 idx dword (+ __shfl broadcast),
//    10 gathers (quarter-wave reads a 256-B permuted row-slice), 2 regular
//    contiguous dwordx4 stores (write stream aggregates in L2 write-back;
//    nt stores sink at ~2.4 TB/s and cost ~2 us -- R7 vs R10)
// Cost model (validated R2/R9/R10): TA/L1 line-touch ~4 cyc/128-B line/CU.
// Main kernel ~12.9K lines/CU -> ~24.6 us wall; measured ~25. Gather lines
// irreducible at fp16 (fp8 fails accuracy: 2^-4*5.5 >> 0.0388 threshold).
// Fallback: fp32 single-dispatch kernel if ws_size < 4 MB.

#define ROWS_TOTAL (1024 * 64)
#define TROWS 8000
#define TD 256

typedef float v4f __attribute__((ext_vector_type(4)));
typedef _Float16 h8 __attribute__((ext_vector_type(8)));

// ---- cvt: fp32 table -> 2-slice permuted fp16 in ws ----
// tid = row*32 + s*16 + i  ->  16-B chunk = dims [128s+4i,+4) U [128s+64+4i,+4)
__global__ __launch_bounds__(256)
void cvt_perm2(const float* __restrict__ t, _Float16* __restrict__ o) {
    const int tid = blockIdx.x * 256 + threadIdx.x;   // 0 .. 256000
    const int row = tid >> 5;
    const int s   = (tid >> 4) & 1;
    const int i   = tid & 15;
    if (row >= TROWS) return;
    const float* src = t + (size_t)row * TD + s * 128 + 4 * i;
    v4f a = *reinterpret_cast<const v4f*>(src);        // dims 128s+4i ..
    v4f b = *reinterpret_cast<const v4f*>(src + 64);   // dims 128s+64+4i ..
    h8 r;
    r[0] = (_Float16)a.x; r[1] = (_Float16)a.y;
    r[2] = (_Float16)a.z; r[3] = (_Float16)a.w;
    r[4] = (_Float16)b.x; r[5] = (_Float16)b.y;
    r[6] = (_Float16)b.z; r[7] = (_Float16)b.w;
    __builtin_nontemporal_store(r, reinterpret_cast<h8*>(o + (size_t)tid * 8));
}

// ---- main: 4 rows x 1 half-slice per wave; 13 VMEM instrs ----
__global__ __launch_bounds__(256)
void char2vec_w2(const int* __restrict__ x,
                 const _Float16* __restrict__ tb,
                 float* __restrict__ out) {
    const int l  = threadIdx.x & 63;
    const int wv = threadIdx.x >> 6;
    const int q  = l >> 4;                 // quarter -> row offset
    const int i  = l & 15;                 // 16-B chunk within half-slice

    const int s       = blockIdx.x & 1;    // d-half; blockIdx%8 -> XCD parity
    const int rowbase = (blockIdx.x >> 1) * 16 + wv * 4;
    const int row     = rowbase + q;

    // 40 indices for the 4-row group in lanes 0..39 (one dword instr).
    const int t = x[rowbase * 10 + (l < 40 ? l : 39)];

    int idx[10];
#pragma unroll
    for (int c = 0; c < 10; ++c) idx[c] = __shfl(t, q * 10 + c);

    // 10 independent gathers; quarter-wave reads a 256-B permuted row-slice.
    h8 v[10];
#pragma unroll
    for (int c = 0; c < 10; ++c)
        v[c] = *reinterpret_cast<const h8*>(
            tb + (size_t)idx[c] * TD + s * 128 + i * 8);

    const float w[10] = {10.f / 55.f, 9.f / 55.f, 8.f / 55.f, 7.f / 55.f,
                         6.f / 55.f,  5.f / 55.f, 4.f / 55.f, 3.f / 55.f,
                         2.f / 55.f,  1.f / 55.f};

    float acc[8] = {0, 0, 0, 0, 0, 0, 0, 0};
#pragma unroll
    for (int c = 0; c < 10; ++c) {
#pragma unroll
        for (int e = 0; e < 8; ++e)
            acc[e] = fmaf((float)v[c][e], w[c], acc[e]);
    }

    // REGULAR stores; each instr writes 4 contiguous 256-B runs.
    v4f lo = {acc[0], acc[1], acc[2], acc[3]};   // dims 128s+4i ..
    v4f hi = {acc[4], acc[5], acc[6], acc[7]};   // dims 128s+64+4i ..
    float* orow = out + (size_t)row * TD + s * 128;
    *reinterpret_cast<v4f*>(orow + 4 * i)      = lo;
    *reinterpret_cast<v4f*>(orow + 64 + 4 * i) = hi;
}

// ---- fp32 single-dispatch fallback if ws too small ----
__global__ __launch_bounds__(256)
void char2vec_sliced2(const int* __restrict__ x,
                      const float* __restrict__ table,
                      float* __restrict__ out) {
    const int slice = blockIdx.x & 7;
    const int rgrp  = blockIdx.x >> 3;
    const int wave  = threadIdx.x >> 6;
    const int lane  = threadIdx.x & 63;

    const int row0 = rgrp * 64 + wave * 16 + (lane >> 3) * 2;
    const int row1 = row0 + 1;
    const int d    = slice * 32 + (lane & 7) * 4;

    const int2* __restrict__ xa = reinterpret_cast<const int2*>(x + row0 * 10);
    const int2* __restrict__ xb = reinterpret_cast<const int2*>(x + row1 * 10);
    int2 pa[5], pb[5];
#pragma unroll
    for (int i = 0; i < 5; ++i) pa[i] = xa[i];
#pragma unroll
    for (int i = 0; i < 5; ++i) pb[i] = xb[i];

    int ia[10], ib[10];
#pragma unroll
    for (int i = 0; i < 5; ++i) {
        ia[2 * i] = pa[i].x; ia[2 * i + 1] = pa[i].y;
        ib[2 * i] = pb[i].x; ib[2 * i + 1] = pb[i].y;
    }

    v4f va[10], vb[10];
#pragma unroll
    for (int c = 0; c < 10; ++c)
        va[c] = *reinterpret_cast<const v4f*>(table + (size_t)ia[c] * TD + d);
#pragma unroll
    for (int c = 0; c < 10; ++c)
        vb[c] = *reinterpret_cast<const v4f*>(table + (size_t)ib[c] * TD + d);

    const float w[10] = {10.f / 55.f, 9.f / 55.f, 8.f / 55.f, 7.f / 55.f,
                         6.f / 55.f,  5.f / 55.f, 4.f / 55.f, 3.f / 55.f,
                         2.f / 55.f,  1.f / 55.f};

    v4f acc0 = (v4f)0.0f, acc1 = (v4f)0.0f;
#pragma unroll
    for (int c = 0; c < 10; ++c) {
        acc0 += va[c] * w[c];
        acc1 += vb[c] * w[c];
    }

    *reinterpret_cast<v4f*>(out + (size_t)row0 * TD + d) = acc0;
    *reinterpret_cast<v4f*>(out + (size_t)row1 * TD + d) = acc1;
}

extern "C" void kernel_launch(void* const* d_in, const int* in_sizes, int n_in,
                              void* d_out, int out_size, void* d_ws, size_t ws_size,
                              hipStream_t stream) {
    const int*   x     = (const int*)d_in[0];
    const float* table = (const float*)d_in[1];
    float*       out   = (float*)d_out;

    const size_t f16_bytes = (size_t)TROWS * TD * sizeof(_Float16);

    if (ws_size >= f16_bytes) {
        _Float16* tb = (_Float16*)d_ws;
        // 8000 rows * 32 chunks / 256 = 1000 blocks
        cvt_perm2<<<(TROWS * 32 + 255) / 256, 256, 0, stream>>>(table, tb);
        // 16 rows x 2 slices: 65536/16*2 = 8192 blocks
        char2vec_w2<<<(ROWS_TOTAL / 16) * 2, 256, 0, stream>>>(x, tb, out);
    } else {
        const int blocks = (ROWS_TOTAL / 64) * 8;   // 8192
        char2vec_sliced2<<<blocks, 256, 0, stream>>>(x, table, out);
    }
}